// Round 4
// baseline (135.150 us; speedup 1.0000x reference)
//
#include <hip/hip_runtime.h>
#include <math.h>

#define BB 4
#define NN 100000
#define KK 128
#define HB 256   // threads per block
#define HH 2     // hits per thread
#define GX ((NN + HB * HH - 1) / (HB * HH))   // 196 blocks in x
#define NBLK (GX * BB)                         // 784 total k_main blocks

// ws layout:
// [0,     4096): unsigned long long packed[B*K]   key = bits(clip(beta))<<32 | ~n
// [4096, 12288): float4 sobj[B*K]  {x_alpha, y_alpha, q_alpha*exf, exf}
// [12288,12352): float acc[16]   (8: exf_sum, 9: (1-beta_alpha)*exf sum)
// [12416, 12416 + NBLK*32): float part[NBLK][8]  per-block partials (no atomics)
//   comp: 0 att, 1 rep, 2 noise_beta, 3 noise_cnt, 4 p_sum, 5 e, 6 pos, 7 time

__device__ __forceinline__ float clipb(float b) {
    return fminf(fmaxf(b, 1e-4f), 1.0f - 1e-4f);
}

// argmax over q == argmax over clip(beta) (monotone). Positive-float bits are
// order-preserving; ~n breaks ties toward smaller n (jnp.argmax semantics).
__global__ void k_argmax(const float* __restrict__ beta,
                         const int* __restrict__ tidx,
                         unsigned long long* __restrict__ packed) {
    int b = blockIdx.y;
    __shared__ unsigned long long smax[KK];
    for (int t = threadIdx.x; t < KK; t += blockDim.x) smax[t] = 0ULL;
    __syncthreads();
    const float* betab = beta + b * NN;
    const int*   tib   = tidx + b * NN;
    for (int n = blockIdx.x * blockDim.x + threadIdx.x; n < NN;
         n += gridDim.x * blockDim.x) {
        int obj = tib[n] - 1;
        if (obj >= 0) {
            unsigned hi = __float_as_uint(clipb(betab[n]));
            unsigned long long key = ((unsigned long long)hi << 32) |
                                     (unsigned long long)(0xFFFFFFFFu - (unsigned)n);
            atomicMax(&smax[obj], key);
        }
    }
    __syncthreads();
    for (int t = threadIdx.x; t < KK; t += blockDim.x) {
        unsigned long long v = smax[t];
        if (v) atomicMax(&packed[b * KK + t], v);
    }
}

__global__ void k_gather(const unsigned long long* __restrict__ packed,
                         const float2* __restrict__ cc,
                         float4* __restrict__ sobj,
                         float* __restrict__ acc) {
    int t = blockIdx.x * blockDim.x + threadIdx.x;
    if (t >= BB * KK) return;
    int b = t / KK;
    unsigned long long v = packed[t];
    float4 o = make_float4(0.f, 0.f, 0.f, 0.f);
    if (v) {
        unsigned n = 0xFFFFFFFFu - (unsigned)(v & 0xFFFFFFFFu);
        float ba = __uint_as_float((unsigned)(v >> 32));   // clipped beta at alpha
        float at = atanhf(ba);
        float2 c = cc[b * NN + (int)n];
        o.x = c.x; o.y = c.y; o.z = at * at + 0.5f; o.w = 1.0f;  // Q_MIN=0.5
        atomicAdd(&acc[8], 1.0f);
        atomicAdd(&acc[9], 1.0f - ba);
    }
    sobj[t] = o;
}

__global__ void __launch_bounds__(HB) k_main(
    const float*  __restrict__ beta, const float2* __restrict__ cc,
    const float*  __restrict__ pe,   const float2* __restrict__ pp,
    const float*  __restrict__ pt,   const float*  __restrict__ te,
    const float2* __restrict__ tp,   const float*  __restrict__ tt,
    const int*    __restrict__ tidx, const float4* __restrict__ sobjg,
    float* __restrict__ part) {
    int b = blockIdx.y;
    __shared__ float4 sobj[KK];
    __shared__ float sred[4][8];
    for (int t = threadIdx.x; t < KK; t += HB) sobj[t] = sobjg[b * KK + t];

    int n0 = blockIdx.x * (HB * HH) + threadIdx.x;
    int n1 = n0 + HB;
    bool v0 = n0 < NN, v1 = n1 < NN;
    int i0 = b * NN + (v0 ? n0 : 0);
    int i1 = b * NN + (v1 ? n1 : 0);

    // hoist all per-hit global loads so HBM latency overlaps the k-loop
    float2 c0 = cc[i0],  c1 = cc[i1];
    float bc0 = clipb(beta[i0]), bc1 = clipb(beta[i1]);
    int   t0  = tidx[i0], t1 = tidx[i1];
    float pe0 = pe[i0], pe1 = pe[i1], te0 = te[i0], te1 = te[i1];
    float pt0 = pt[i0], pt1 = pt[i1], tt0 = tt[i0], tt1 = tt[i1];
    float2 pp0 = pp[i0], pp1 = pp[i1], tp0 = tp[i0], tp1 = tp[i1];

    __syncthreads();

    float rep0 = 0.f, rep1 = 0.f;
    #pragma unroll 8
    for (int k = 0; k < KK; ++k) {
        float4 o = sobj[k];                 // uniform addr -> broadcast
        float dx0 = c0.x - o.x, dy0 = c0.y - o.y;
        float dx1 = c1.x - o.x, dy1 = c1.y - o.y;
        float s0 = fmaf(dx0, dx0, fmaf(dy0, dy0, 1e-12f));
        float s1 = fmaf(dx1, dx1, fmaf(dy1, dy1, 1e-12f));
        float d0 = __builtin_amdgcn_sqrtf(s0);
        float d1 = __builtin_amdgcn_sqrtf(s1);
        rep0 = fmaf(o.z, fmaxf(1.0f - d0, 0.0f), rep0);
        rep1 = fmaf(o.z, fmaxf(1.0f - d1, 0.0f), rep1);
    }

    float p_att = 0.f, p_rep = 0.f, p_nb = 0.f, p_nc = 0.f;
    float p_ps = 0.f, p_e = 0.f, p_pos = 0.f, p_tm = 0.f;

    #pragma unroll
    for (int h = 0; h < HH; ++h) {
        bool  vld = h ? v1 : v0;   if (!vld) continue;
        float rep = h ? rep1 : rep0;
        float2 c  = h ? c1 : c0;
        float bc  = h ? bc1 : bc0;
        int   ti  = h ? t1 : t0;
        float at  = atanhf(bc);
        float at2 = at * at;
        float q   = at2 + 0.5f;
        int   obj = ti - 1;

        if (obj >= 0) {                     // member: move own term rep -> att
            float4 o = sobj[obj];
            float dx = c.x - o.x, dy = c.y - o.y;
            float s = fmaf(dx, dx, fmaf(dy, dy, 1e-12f));
            float d = __builtin_amdgcn_sqrtf(s);
            rep   -= o.z * fmaxf(1.0f - d, 0.0f);
            p_att += q * (o.z * s);         // dist^2 == s
        }
        p_rep += q * rep;

        if (ti == 0) {                      // noise hit
            p_nb += bc;
            p_nc += 1.0f;
        } else {                            // payload (beta-weighted, non-noise)
            p_ps += at2;
            float de = (h ? pe1 : pe0) - (h ? te1 : te0);
            float a  = fabsf(de);
            float hb = (a <= 2.0f) ? (0.5f * de * de) : (2.0f * (a - 1.0f));
            p_e  += at2 * hb;
            float2 ppv = h ? pp1 : pp0, tpv = h ? tp1 : tp0;
            float dpx = ppv.x - tpv.x, dpy = ppv.y - tpv.y;
            p_pos += at2 * (dpx * dpx + dpy * dpy);
            float dt = (h ? pt1 : pt0) - (h ? tt1 : tt0);
            p_tm += at2 * dt * dt;
        }
    }

    float vals[8] = {p_att, p_rep, p_nb, p_nc, p_ps, p_e, p_pos, p_tm};
    int lane = threadIdx.x & 63, wave = threadIdx.x >> 6;
    #pragma unroll
    for (int i = 0; i < 8; ++i) {
        float v = vals[i];
        #pragma unroll
        for (int off = 32; off > 0; off >>= 1) v += __shfl_down(v, off, 64);
        if (lane == 0) sred[wave][i] = v;
    }
    __syncthreads();
    if (threadIdx.x < 8) {
        float s = sred[0][threadIdx.x] + sred[1][threadIdx.x] +
                  sred[2][threadIdx.x] + sred[3][threadIdx.x];
        int bid = b * GX + blockIdx.x;
        part[bid * 8 + threadIdx.x] = s;    // plain store, NO atomics
    }
}

// single wave: lane L sums component (L&7) over rows (L>>3)+8j, coalesced.
__global__ void __launch_bounds__(64) k_final(const float* __restrict__ part,
                                              const float* __restrict__ acc,
                                              float* __restrict__ out) {
    int lane = threadIdx.x;
    int comp = lane & 7;
    float v = 0.f;
    for (int r = lane >> 3; r < NBLK; r += 8)
        v += part[r * 8 + comp];
    v += __shfl_xor(v, 8, 64);
    v += __shfl_xor(v, 16, 64);
    v += __shfl_xor(v, 32, 64);            // lane c (c<8) holds total of comp c
    float tot[8];
    #pragma unroll
    for (int c = 0; c < 8; ++c) tot[c] = __shfl(v, c, 64);
    if (lane == 0) {
        float inv_n  = 1.0f / (float)(BB * NN);
        float n_obj  = fmaxf(acc[8], 1.0f);
        float L_beta = acc[9] / n_obj + tot[2] / fmaxf(tot[3], 1.0f);  // S_B=1
        float p_sum  = fmaxf(tot[4], 1e-6f);
        out[0] = tot[0] * inv_n + tot[1] * inv_n + L_beta +
                 (tot[5] + tot[6] + tot[7]) / p_sum;
    }
}

extern "C" void kernel_launch(void* const* d_in, const int* in_sizes, int n_in,
                              void* d_out, int out_size, void* d_ws, size_t ws_size,
                              hipStream_t stream) {
    const float*  beta = (const float*)d_in[0];
    const float2* cc   = (const float2*)d_in[1];
    const float*  pe   = (const float*)d_in[2];
    const float2* pp   = (const float2*)d_in[3];
    const float*  pt   = (const float*)d_in[4];
    const float*  te   = (const float*)d_in[5];
    const float2* tp   = (const float2*)d_in[6];
    const float*  tt   = (const float*)d_in[7];
    const int*    ti   = (const int*)d_in[8];

    unsigned long long* packed = (unsigned long long*)d_ws;
    float4* sobj = (float4*)((char*)d_ws + 4096);
    float*  acc  = (float*)((char*)d_ws + 12288);
    float*  part = (float*)((char*)d_ws + 12416);
    float*  out  = (float*)d_out;

    // zero packed[] and acc[] (sobj and part are fully overwritten)
    hipMemsetAsync(d_ws, 0, 12352, stream);

    k_argmax<<<dim3(128, BB), 256, 0, stream>>>(beta, ti, packed);
    k_gather<<<dim3(2), 256, 0, stream>>>(packed, cc, sobj, acc);
    k_main<<<dim3(GX, BB), HB, 0, stream>>>(
        beta, cc, pe, pp, pt, te, tp, tt, ti, sobj, part);
    k_final<<<1, 64, 0, stream>>>(part, acc, out);
}

// Round 5
// 122.549 us; speedup vs baseline: 1.1028x; 1.1028x over previous
//
#include <hip/hip_runtime.h>
#include <math.h>

#define BB 4
#define NN 100000
#define KK 128
#define HB 256   // threads per block
#define HH 4     // hits per thread: one sobj[k] LDS read feeds HH pairs
#define GX ((NN + HB * HH - 1) / (HB * HH))   // 98 blocks in x
#define NBLK (GX * BB)                         // 392 k_main blocks

// ws layout:
// [0,    4096): unsigned long long packed[B*K]   key = bits(clip(beta))<<32 | ~n
// [4096, 4096 + NBLK*32): float part[NBLK][8]    per-block partials (no atomics)
//   comp: 0 att, 1 rep, 2 noise_beta, 3 noise_cnt, 4 p_sum, 5 e, 6 pos, 7 time

__device__ __forceinline__ float clipb(float b) {
    return fminf(fmaxf(b, 1e-4f), 1.0f - 1e-4f);
}

// argmax over q == argmax over clip(beta) (monotone). Positive-float bits are
// order-preserving; ~n breaks ties toward smaller n (jnp.argmax semantics).
__global__ void k_argmax(const float* __restrict__ beta,
                         const int* __restrict__ tidx,
                         unsigned long long* __restrict__ packed) {
    int b = blockIdx.y;
    __shared__ unsigned long long smax[KK];
    for (int t = threadIdx.x; t < KK; t += blockDim.x) smax[t] = 0ULL;
    __syncthreads();
    const float* betab = beta + b * NN;
    const int*   tib   = tidx + b * NN;
    for (int n = blockIdx.x * blockDim.x + threadIdx.x; n < NN;
         n += gridDim.x * blockDim.x) {
        int obj = tib[n] - 1;
        if (obj >= 0) {
            unsigned hi = __float_as_uint(clipb(betab[n]));
            unsigned long long key = ((unsigned long long)hi << 32) |
                                     (unsigned long long)(0xFFFFFFFFu - (unsigned)n);
            atomicMax(&smax[obj], key);
        }
    }
    __syncthreads();
    for (int t = threadIdx.x; t < KK; t += blockDim.x) {
        unsigned long long v = smax[t];
        if (v) atomicMax(&packed[b * KK + t], v);
    }
}

__global__ void __launch_bounds__(HB) k_main(
    const float*  __restrict__ beta, const float2* __restrict__ cc,
    const float*  __restrict__ pe,   const float2* __restrict__ pp,
    const float*  __restrict__ pt,   const float*  __restrict__ te,
    const float2* __restrict__ tp,   const float*  __restrict__ tt,
    const int*    __restrict__ tidx,
    const unsigned long long* __restrict__ packed,
    float* __restrict__ part) {
    int b = blockIdx.y;
    __shared__ float4 sobj[KK];     // {x_alpha, y_alpha, q_alpha*exf, exf}
    __shared__ float sred[4][8];

    // self-gather: decode condensation points from packed[] (512 B, L2-hot)
    if (threadIdx.x < KK) {
        unsigned long long v = packed[b * KK + threadIdx.x];
        float4 o = make_float4(0.f, 0.f, 0.f, 0.f);
        if (v) {
            unsigned n = 0xFFFFFFFFu - (unsigned)(v & 0xFFFFFFFFu);
            float ba = __uint_as_float((unsigned)(v >> 32));  // clip(beta_alpha)
            float at = atanhf(ba);
            float2 c = cc[b * NN + (int)n];
            o = make_float4(c.x, c.y, at * at + 0.5f, 1.f);   // Q_MIN = 0.5
        }
        sobj[threadIdx.x] = o;
    }

    int base = blockIdx.x * (HB * HH) + threadIdx.x;
    bool vv[HH]; int ii[HH]; float2 ch[HH]; float rp[HH];
    #pragma unroll
    for (int h = 0; h < HH; ++h) {
        int n = base + h * HB;
        vv[h] = n < NN;
        ii[h] = b * NN + (vv[h] ? n : 0);
        ch[h] = cc[ii[h]];
        rp[h] = 0.f;
    }
    __syncthreads();

    #pragma unroll 4
    for (int k = 0; k < KK; ++k) {
        float4 o = sobj[k];                 // uniform addr -> broadcast
        #pragma unroll
        for (int h = 0; h < HH; ++h) {
            float dx = ch[h].x - o.x, dy = ch[h].y - o.y;
            float s  = fmaf(dx, dx, fmaf(dy, dy, 1e-12f));
            float d  = __builtin_amdgcn_sqrtf(s);   // raw v_sqrt_f32
            rp[h] = fmaf(o.z, fmaxf(1.0f - d, 0.0f), rp[h]);
        }
    }

    float p_att = 0.f, p_rep = 0.f, p_nb = 0.f, p_nc = 0.f;
    float p_ps = 0.f, p_e = 0.f, p_pos = 0.f, p_tm = 0.f;

    #pragma unroll
    for (int h = 0; h < HH; ++h) {
        if (!vv[h]) continue;
        int   idx = ii[h];
        float rep = rp[h];
        float bc  = clipb(beta[idx]);
        float at  = atanhf(bc);
        float at2 = at * at;
        float q   = at2 + 0.5f;
        int   ti  = tidx[idx];
        int   obj = ti - 1;

        if (obj >= 0) {                     // member: move own term rep -> att
            float4 o = sobj[obj];
            float dx = ch[h].x - o.x, dy = ch[h].y - o.y;
            float s = fmaf(dx, dx, fmaf(dy, dy, 1e-12f));
            float d = __builtin_amdgcn_sqrtf(s);
            rep   -= o.z * fmaxf(1.0f - d, 0.0f);
            p_att += q * (o.z * s);         // dist^2 == s (incl. 1e-12 eps)
        }
        p_rep += q * rep;

        if (ti == 0) {                      // noise hit
            p_nb += bc;
            p_nc += 1.0f;
        } else {                            // payload (beta-weighted, non-noise)
            p_ps += at2;
            float de = pe[idx] - te[idx];
            float a  = fabsf(de);
            float hb = (a <= 2.0f) ? (0.5f * de * de) : (2.0f * (a - 1.0f));
            p_e  += at2 * hb;
            float2 ppv = pp[idx], tpv = tp[idx];
            float dpx = ppv.x - tpv.x, dpy = ppv.y - tpv.y;
            p_pos += at2 * (dpx * dpx + dpy * dpy);
            float dt = pt[idx] - tt[idx];
            p_tm += at2 * dt * dt;
        }
    }

    float vals[8] = {p_att, p_rep, p_nb, p_nc, p_ps, p_e, p_pos, p_tm};
    int lane = threadIdx.x & 63, wave = threadIdx.x >> 6;
    #pragma unroll
    for (int i = 0; i < 8; ++i) {
        float v = vals[i];
        #pragma unroll
        for (int off = 32; off > 0; off >>= 1) v += __shfl_down(v, off, 64);
        if (lane == 0) sred[wave][i] = v;
    }
    __syncthreads();
    if (threadIdx.x < 8) {
        float s = sred[0][threadIdx.x] + sred[1][threadIdx.x] +
                  sred[2][threadIdx.x] + sred[3][threadIdx.x];
        part[(b * GX + blockIdx.x) * 8 + threadIdx.x] = s;   // plain store
    }
}

// single wave: reduce part[NBLK][8] + derive beta_alpha terms from packed bits
__global__ void __launch_bounds__(64) k_final(
    const float* __restrict__ part,
    const unsigned long long* __restrict__ packed,
    float* __restrict__ out) {
    int lane = threadIdx.x;

    // beta_alpha / n_obj terms straight from the packed keys (no gather)
    float nobj = 0.f, sba = 0.f;
    for (int t = lane; t < BB * KK; t += 64) {
        unsigned long long v = packed[t];
        if (v) {
            nobj += 1.f;
            sba  += 1.0f - __uint_as_float((unsigned)(v >> 32));
        }
    }
    #pragma unroll
    for (int off = 32; off > 0; off >>= 1) {
        nobj += __shfl_xor(nobj, off, 64);
        sba  += __shfl_xor(sba, off, 64);
    }

    // lane L sums component (L&7) over rows (L>>3)+8j (coalesced)
    int comp = lane & 7;
    float v = 0.f;
    for (int r = lane >> 3; r < NBLK; r += 8)
        v += part[r * 8 + comp];
    v += __shfl_xor(v, 8, 64);
    v += __shfl_xor(v, 16, 64);
    v += __shfl_xor(v, 32, 64);            // lane c (c<8) holds total of comp c
    float tot[8];
    #pragma unroll
    for (int c = 0; c < 8; ++c) tot[c] = __shfl(v, c, 64);

    if (lane == 0) {
        float inv_n  = 1.0f / (float)(BB * NN);
        float L_beta = sba / fmaxf(nobj, 1.0f) +
                       tot[2] / fmaxf(tot[3], 1.0f);         // S_B = 1
        float p_sum  = fmaxf(tot[4], 1e-6f);
        out[0] = tot[0] * inv_n + tot[1] * inv_n + L_beta +
                 (tot[5] + tot[6] + tot[7]) / p_sum;
    }
}

extern "C" void kernel_launch(void* const* d_in, const int* in_sizes, int n_in,
                              void* d_out, int out_size, void* d_ws, size_t ws_size,
                              hipStream_t stream) {
    const float*  beta = (const float*)d_in[0];
    const float2* cc   = (const float2*)d_in[1];
    const float*  pe   = (const float*)d_in[2];
    const float2* pp   = (const float2*)d_in[3];
    const float*  pt   = (const float*)d_in[4];
    const float*  te   = (const float*)d_in[5];
    const float2* tp   = (const float2*)d_in[6];
    const float*  tt   = (const float*)d_in[7];
    const int*    ti   = (const int*)d_in[8];

    unsigned long long* packed = (unsigned long long*)d_ws;
    float* part = (float*)((char*)d_ws + 4096);
    float* out  = (float*)d_out;

    hipMemsetAsync(packed, 0, 4096, stream);   // only packed[] needs zeroing
    k_argmax<<<dim3(128, BB), 256, 0, stream>>>(beta, ti, packed);
    k_main<<<dim3(GX, BB), HB, 0, stream>>>(
        beta, cc, pe, pp, pt, te, tp, tt, ti, packed, part);
    k_final<<<1, 64, 0, stream>>>(part, packed, out);
}